// Round 10
// baseline (3661.641 us; speedup 1.0000x reference)
//
#include <hip/hip_runtime.h>
#include <hip/hip_bf16.h>

#define BB 4
#define SS 4096
#define DD 512
#define LWW 512
#define CC 64
#define NCH 64
#define SCAN_SMEM 111104

typedef unsigned short u16;
using fragAB = __attribute__((ext_vector_type(8))) short;
using fragC  = __attribute__((ext_vector_type(4))) float;
using u16x4  = __attribute__((ext_vector_type(4))) short;

__device__ __forceinline__ short f2bf(float f){
  unsigned u = __float_as_uint(f);
  u = (u + 0x7FFFu + ((u >> 16) & 1u)) >> 16;
  return (short)u;
}
__device__ __forceinline__ float bf2f(short s){
  return __uint_as_float(((unsigned)(u16)s) << 16);
}
__device__ __forceinline__ fragC zeroC(){ fragC z = {0.f,0.f,0.f,0.f}; return z; }

__device__ __forceinline__ fragAB frag_bf16g(const u16* __restrict__ base, int ld, int r0, int k0, int lane){
  return *(const fragAB*)(base + (size_t)(r0 + (lane & 15)) * ld + k0 + ((lane >> 4) << 3));
}
__device__ __forceinline__ fragAB frag_lds(const short* base, int ld, int r0, int k0, int lane){
  return *(const fragAB*)(base + (r0 + (lane & 15)) * ld + k0 + ((lane >> 4) << 3));
}
#define MFMA16(a,b,c) __builtin_amdgcn_mfma_f32_16x16x32_bf16(a,b,c,0,0,0)

// ---- system-coherent (Infinity-Cache) access ----
__device__ __forceinline__ void ld_sys(fragAB& r, const u16* p){
  asm volatile("global_load_dwordx4 %0, %1, off sc0 sc1" : "=v"(r) : "v"(p) : "memory");
}
__device__ __forceinline__ void st_sys8(u16* p, u16x4 v){
  asm volatile("global_store_dwordx2 %0, %1, off sc0 sc1" :: "v"(p), "v"(v) : "memory");
}
__device__ __forceinline__ void st_sys16(u16* p, fragAB v){
  asm volatile("global_store_dwordx4 %0, %1, off sc0 sc1" :: "v"(p), "v"(v) : "memory");
}
#define WAITVM(N) do { asm volatile("s_waitcnt vmcnt(" #N ")" ::: "memory"); \
                       __builtin_amdgcn_sched_barrier(0); } while (0)

// tiled exchange layout [k/16][64 c][16]
__device__ __forceinline__ const u16* taddr(const u16* base, int c, int kq){
  return base + (((size_t)((kq >> 4)*64 + c)) << 4) + (kq & 15);
}

// ---------------- split distributed per-batch barrier ----------------
__device__ __forceinline__ void bar_arrive(unsigned* slots, unsigned phase, int tl){
  asm volatile("s_waitcnt vmcnt(0)" ::: "memory");
  __builtin_amdgcn_sched_barrier(0);
  __syncthreads();
  if (threadIdx.x == 0)
    __hip_atomic_store(slots + (size_t)tl*32, phase, __ATOMIC_RELAXED, __HIP_MEMORY_SCOPE_AGENT);
}
__device__ __forceinline__ void bar_wait(unsigned* slots, unsigned phase){
  if (threadIdx.x < 64){
    bool mine = threadIdx.x < 32;
    unsigned* sp = slots + (size_t)(threadIdx.x & 31)*32;
    for (;;){
      unsigned v = mine ? __hip_atomic_load(sp, __ATOMIC_RELAXED, __HIP_MEMORY_SCOPE_AGENT) : phase;
      if (__all((int)(v >= phase))) break;
      __builtin_amdgcn_s_sleep(1);
    }
  }
  __syncthreads();
}

// ---------------- fp32 -> bf16 conversions + bar zero ----------------
__global__ __launch_bounds__(256) void k_cvt(const float* __restrict__ x,
    const float* __restrict__ Wq, const float* __restrict__ Wk, const float* __restrict__ Wv,
    u16* __restrict__ xb, u16* __restrict__ Wc, unsigned* __restrict__ bar){
  size_t i = (size_t)blockIdx.x * 256 + threadIdx.x;
  if (blockIdx.x == 0){
    for (int z = threadIdx.x; z < 4096; z += 256) bar[z] = 0u;
  }
  const size_t NX4 = (size_t)BB*SS*DD/4;
  const size_t NW4 = (size_t)DD*DD/4;
  if (i < NX4){
    float4 v = ((const float4*)x)[i];
    u16x4 o = { f2bf(v.x), f2bf(v.y), f2bf(v.z), f2bf(v.w) };
    *(u16x4*)(xb + 4*i) = o;
  } else if (i < NX4 + 3*NW4){
    size_t j = i - NX4;
    const float* src = (j < NW4) ? Wq : (j < 2*NW4) ? Wk : Wv;
    size_t jj = j % NW4;
    float4 v = ((const float4*)src)[jj];
    u16x4 o = { f2bf(v.x), f2bf(v.y), f2bf(v.z), f2bf(v.w) };
    *(u16x4*)(Wc + 4*j) = o;
  }
}

// ---------------- Q,K,V projections ----------------
__global__ __launch_bounds__(256) void k_proj(const u16* __restrict__ xb,
    const u16* __restrict__ Wc,
    u16* __restrict__ Qb, u16* __restrict__ Kb, float* __restrict__ V){
  int mt = blockIdx.x / 12, nt = blockIdx.x % 12;
  int lane = threadIdx.x & 63, wid = threadIdx.x >> 6;
  int m0 = mt * 64 + wid * 16;
  const u16* Bp = Wc + (size_t)nt * 128 * DD;
  fragC acc[8];
#pragma unroll
  for (int i = 0; i < 8; ++i) acc[i] = zeroC();
  for (int k0 = 0; k0 < DD; k0 += 32){
    fragAB a = frag_bf16g(xb, DD, m0, k0, lane);
#pragma unroll
    for (int nf = 0; nf < 8; ++nf)
      acc[nf] = MFMA16(a, frag_bf16g(Bp, DD, nf*16, k0, lane), acc[nf]);
  }
#pragma unroll
  for (int nf = 0; nf < 8; ++nf){
#pragma unroll
    for (int r = 0; r < 4; ++r){
      int m = m0 + ((lane >> 4) << 2) + r;
      int col = nt*128 + nf*16 + (lane & 15);
      float v = acc[nf][r];
      if (nt < 4)      Qb[(size_t)m*DD + col]        = (u16)f2bf(v);
      else if (nt < 8) Kb[(size_t)m*DD + col - 512]  = (u16)f2bf(v);
      else             V [(size_t)m*DD + col - 1024] = v;
    }
  }
}

// ---------------- l2-normalize Q,K rows ----------------
__global__ __launch_bounds__(256) void k_norm(u16* __restrict__ Qb, u16* __restrict__ Kb){
  int idx = blockIdx.x * 4 + (threadIdx.x >> 6);
  int lane = threadIdx.x & 63;
  u16* p = (idx < BB*SS ? Qb + (size_t)idx * DD
                        : Kb + (size_t)(idx - BB*SS) * DD) + lane * 8;
  fragAB v = *(const fragAB*)p;
  float f[8]; float s = 0.f;
#pragma unroll
  for (int i = 0; i < 8; ++i){ f[i] = bf2f(v[i]); s += f[i]*f[i]; }
#pragma unroll
  for (int o = 32; o > 0; o >>= 1) s += __shfl_xor(s, o, 64);
  float inv = 1.f / fmaxf(sqrtf(s), 1e-12f);
  fragAB o8;
#pragma unroll
  for (int i = 0; i < 8; ++i) o8[i] = f2bf(f[i] * inv);
  *(fragAB*)p = o8;
}

// ---------------- transpose K ----------------
__global__ __launch_bounds__(256) void k_trans(const u16* __restrict__ Kb, u16* __restrict__ KT){
  __shared__ short tile[64][68];
  int blk = blockIdx.x;
  int b = blk >> 9, rem = blk & 511;
  int st = rem >> 3, dt = rem & 7;
  int s0 = st*64, d0 = dt*64;
  int sr = threadIdx.x & 63, q = threadIdx.x >> 6;
  const u16* src = Kb + ((size_t)b*SS + s0 + sr)*DD + d0 + q*16;
  fragAB v0 = *(const fragAB*)src;
  fragAB v1 = *(const fragAB*)(src + 8);
#pragma unroll
  for (int i = 0; i < 8; ++i){ tile[sr][q*16+i] = v0[i]; tile[sr][q*16+8+i] = v1[i]; }
  __syncthreads();
  fragAB o0, o1;
#pragma unroll
  for (int i = 0; i < 8; ++i){ o0[i] = tile[q*16+i][sr]; o1[i] = tile[q*16+8+i][sr]; }
  u16* dst = KT + ((size_t)b*DD + d0 + sr)*SS + s0 + q*16;
  *(fragAB*)dst = o0;
  *(fragAB*)(dst + 8) = o1;
}

// ---------------- gates ----------------
__global__ __launch_bounds__(256) void k_gates(const float* __restrict__ x,
    const float* __restrict__ aw, const float* __restrict__ ab,
    const float* __restrict__ ew, const float* __restrict__ eb,
    const float* __restrict__ tw, const float* __restrict__ tb,
    float* __restrict__ aet){
  __shared__ float part[64][4][3];
  __shared__ float rowsig[64][3];
  int b = blockIdx.x >> 6, t = blockIdx.x & 63;
  int tid = threadIdx.x;
  int r = tid >> 2, p = tid & 3;
  const float4* xp = (const float4*)(x + ((size_t)b*SS + (size_t)t*CC + r) * DD + p * 128);
  const float4* a4 = (const float4*)(aw + p*128);
  const float4* e4 = (const float4*)(ew + p*128);
  const float4* t4 = (const float4*)(tw + p*128);
  float s0 = 0.f, s1 = 0.f, s2 = 0.f;
  for (int i = 0; i < 32; ++i){
    float4 xv = xp[i], av = a4[i], ev = e4[i], tv = t4[i];
    s0 += xv.x*av.x + xv.y*av.y + xv.z*av.z + xv.w*av.w;
    s1 += xv.x*ev.x + xv.y*ev.y + xv.z*ev.z + xv.w*ev.w;
    s2 += xv.x*tv.x + xv.y*tv.y + xv.z*tv.z + xv.w*tv.w;
  }
  part[r][p][0] = s0; part[r][p][1] = s1; part[r][p][2] = s2;
  __syncthreads();
  if (tid < 64){
    float a_ = part[tid][0][0]+part[tid][1][0]+part[tid][2][0]+part[tid][3][0] + ab[0];
    float e_ = part[tid][0][1]+part[tid][1][1]+part[tid][2][1]+part[tid][3][1] + eb[0];
    float t_ = part[tid][0][2]+part[tid][1][2]+part[tid][2][2]+part[tid][3][2] + tb[0];
    rowsig[tid][0] = 1.f/(1.f+expf(-a_));
    rowsig[tid][1] = 1.f/(1.f+expf(-e_));
    rowsig[tid][2] = 1.f/(1.f+expf(-t_));
  }
  __syncthreads();
  if (tid < 3){
    float s = 0.f;
    for (int i = 0; i < 64; ++i) s += rowsig[i][tid];
    aet[((size_t)b*NCH + t)*3 + tid] = s * (1.f/64.f);
  }
}

// ---------------- per-batch context ----------------
struct BCtx {
  const u16 *Kball, *Qball, *KTbat;
  u16 *hk_b, *hq_b, *hkT_b, *dv_b, *w2T_b;
  const float *V_b, *aet_b;
  float *out_b;
  unsigned *slots;
  short *s_w1, *s_w2, *s_pf;
  float *s_b1, *s_mb1, *s_b2, *s_mb2;
};

__device__ __forceinline__ void do_init(const BCtx& C,
    const float* iw1, const float* ib1, const float* iw2, const float* ib2,
    int tid, int wid, int q, int l15, int h0,
    float (&w1f)[16], float (&mw1f)[16], float (&w2f)[16], float (&mw2f)[16],
    float (&actr)[4])
{
#pragma unroll
  for (int nf = 0; nf < 4; ++nf){
    u16x4 pk;
#pragma unroll
    for (int r = 0; r < 4; ++r){
      int hr = q*4 + r;
      int dcol = wid*64 + nf*16 + l15;
      float a = iw1[(size_t)(h0 + hr)*DD + dcol];
      w1f[nf*4+r] = a; mw1f[nf*4+r] = 0.f;
      C.s_w1[hr*520 + dcol] = f2bf(a);
      float c = iw2[(size_t)(h0 + hr)*LWW + dcol];
      w2f[nf*4+r] = c; mw2f[nf*4+r] = 0.f;
      C.s_w2[hr*520 + dcol] = f2bf(c);
      pk[r] = f2bf(c);
    }
    st_sys8(C.w2T_b + (size_t)(wid*64 + nf*16 + l15)*DD + h0 + q*4, pk);
  }
  if (tid < 16){
    C.s_b1[tid] = ib1[h0 + tid]; C.s_mb1[tid] = 0.f;
    C.s_b2[tid] = ib2[h0 + tid]; C.s_mb2[tid] = 0.f;
  }
#pragma unroll
  for (int r = 0; r < 4; ++r) actr[r] = 0.f;
}

__device__ __forceinline__ void do_phaseA(const BCtx& C, int t,
    int tid, int lane, int wid, int q, int l15, int qk, int tl, int h0,
    float (&w1f)[16], float (&mw1f)[16], float (&actr)[4],
    short* s_t, short* s_hk, short* s_hq, float (*s_part)[17], unsigned phA)
{
  if (t > 0){
    fragAB kfr[8];
    {
      const u16* KTm = C.KTbat + (size_t)(t-1)*CC;
#pragma unroll
      for (int nf = 0; nf < 4; ++nf)
#pragma unroll
        for (int kk = 0; kk < 2; ++kk)
          kfr[nf*2+kk] = frag_bf16g(KTm, SS, wid*64 + nf*16, kk*32, lane);
    }
    { // dh K-split across 8 waves
      const int cst = (wid & 3) * 16;
      const int kh  = (wid >> 2) * 256;
      fragAB fa[8];
      fragC a0 = zeroC();
#pragma unroll
      for (int j = 0; j < 8; ++j) ld_sys(fa[j], taddr(C.dv_b, cst + l15, kh + j*32 + qk));
      WAITVM(4);
#pragma unroll
      for (int j = 0; j < 4; ++j) a0 = MFMA16(fa[j], frag_lds(C.s_pf, 520, 0, kh + j*32, lane), a0);
      WAITVM(0);
#pragma unroll
      for (int j = 4; j < 8; ++j) a0 = MFMA16(fa[j], frag_lds(C.s_pf, 520, 0, kh + j*32, lane), a0);
      if (wid >= 4){
#pragma unroll
        for (int r = 0; r < 4; ++r) s_part[cst + q*4 + r][l15] = a0[r];
      }
      __syncthreads();
      if (wid < 4){
#pragma unroll
        for (int r = 0; r < 4; ++r){
          float v = (a0[r] + s_part[cst + q*4 + r][l15]) * actr[r];
          s_t[l15*72 + cst + q*4 + r] = f2bf(v);
        }
      }
      __syncthreads();
    }
    { // g_w1 [16 h][512 d], K = 64 c ; w1/b1 update
      fragC ag[4];
#pragma unroll
      for (int i = 0; i < 4; ++i) ag[i] = zeroC();
#pragma unroll
      for (int kk = 0; kk < 2; ++kk){
        fragAB af = frag_lds(s_t, 72, 0, kk*32, lane);
#pragma unroll
        for (int nf = 0; nf < 4; ++nf)
          ag[nf] = MFMA16(af, kfr[nf*2+kk], ag[nf]);
      }
      const float* g3 = C.aet_b + (size_t)(t-1)*3;
      float ga = g3[0], ge = g3[1], gth = g3[2];
#pragma unroll
      for (int nf = 0; nf < 4; ++nf)
#pragma unroll
        for (int r = 0; r < 4; ++r){
          float g  = ag[nf][r] * (1.f/64.f);
          float m_ = ge*mw1f[nf*4+r] - gth*g;
          float w_ = (1.f-ga)*w1f[nf*4+r] + m_;
          mw1f[nf*4+r] = m_; w1f[nf*4+r] = w_;
          C.s_w1[(q*4+r)*520 + wid*64 + nf*16 + l15] = f2bf(w_);
        }
      if (tid < 16){
        const fragAB* row = (const fragAB*)(s_t + tid*72);
        float s = 0.f;
#pragma unroll
        for (int j = 0; j < 8; ++j){
          fragAB v = row[j];
#pragma unroll
          for (int i = 0; i < 8; ++i) s += bf2f(v[i]);
        }
        float gb = s * (1.f/64.f);
        float m_ = ge*C.s_mb1[tid] - gth*gb;
        float bn = (1.f-ga)*C.s_b1[tid] + m_;
        C.s_mb1[tid] = m_; C.s_b1[tid] = bn;
      }
    }
  }
  __syncthreads();
  { // pre (waves 0-3, K) & hq (waves 4-7, Q)
    const u16* Ac = (wid < 4 ? C.Kball : C.Qball) + (size_t)t*CC*DD;
    int m0 = (wid & 3) * 16;
    fragC acc = zeroC();
    for (int k0 = 0; k0 < DD; k0 += 32)
      acc = MFMA16(frag_bf16g(Ac, DD, m0, k0, lane),
                   frag_lds(C.s_w1, 520, 0, k0, lane), acc);
    float bb = C.s_b1[l15];
    if (wid < 4){
#pragma unroll
      for (int r = 0; r < 4; ++r){
        int c = m0 + q*4 + r;
        float pre = acc[r] + bb;
        float sg  = 1.f/(1.f+expf(-pre));
        float hkv = pre * sg;
        actr[r]   = sg * (1.f + pre * (1.f - sg));
        short hb  = f2bf(hkv);
        s_hk[c*16 + l15] = hb;
        s_t[l15*72 + c]  = hb;
      }
    } else {
#pragma unroll
      for (int r = 0; r < 4; ++r){
        int c = m0 + q*4 + r;
        float hqv = acc[r] + bb;
        float s2  = 1.f/(1.f+expf(-hqv));
        s_hq[c*16 + l15] = f2bf(hqv * s2);
      }
    }
  }
  __syncthreads();
  if (tid < 128){
    st_sys16(C.hk_b + (size_t)tl*1024 + tid*8, *(const fragAB*)(s_hk + tid*8));
  } else if (tid < 256){
    int i = tid - 128;
    st_sys16(C.hq_b + (size_t)tl*1024 + i*8, *(const fragAB*)(s_hq + i*8));
  } else if (tid < 384){
    int i = tid - 256;
    int row = i >> 3, seg = i & 7;
    st_sys16(C.hkT_b + (size_t)(h0 + row)*CC + seg*8, *(const fragAB*)(s_t + row*72 + seg*8));
  }
  bar_arrive(C.slots, phA, tl);
}

__device__ __forceinline__ void do_phaseB(const BCtx& C, int t,
    int tid, int lane, int wid, int q, int l15, int qk, int tl, int d0,
    float (&w2f)[16], float (&mw2f)[16],
    short* s_t, short* s_hk, unsigned phB, size_t W2TBUF)
{
  const u16* Ah = (wid < 4) ? C.hq_b : C.hk_b;
  int m0 = (wid & 3) * 16;
  fragC acc = zeroC();
  fragAB va[4], vb[4], hfr[8];
  float vv[4];
  if (wid >= 4){
#pragma unroll
    for (int r = 0; r < 4; ++r)
      vv[r] = C.V_b[((size_t)t*CC + m0 + q*4 + r)*DD + d0 + l15];
  }
#pragma unroll
  for (int j = 0; j < 4; ++j) ld_sys(va[j], taddr(Ah, m0 + l15, j*32 + qk));
#pragma unroll
  for (int j = 0; j < 4; ++j) ld_sys(vb[j], taddr(Ah, m0 + l15, 128 + j*32 + qk));
  WAITVM(4);
#pragma unroll
  for (int j = 0; j < 4; ++j) acc = MFMA16(va[j], frag_lds(C.s_w2, 520, 0, j*32, lane), acc);
#pragma unroll
  for (int j = 0; j < 4; ++j) ld_sys(va[j], taddr(Ah, m0 + l15, 256 + j*32 + qk));
  WAITVM(4);
#pragma unroll
  for (int j = 0; j < 4; ++j) acc = MFMA16(vb[j], frag_lds(C.s_w2, 520, 0, 128 + j*32, lane), acc);
#pragma unroll
  for (int j = 0; j < 4; ++j) ld_sys(vb[j], taddr(Ah, m0 + l15, 384 + j*32 + qk));
  WAITVM(4);
#pragma unroll
  for (int j = 0; j < 4; ++j) acc = MFMA16(va[j], frag_lds(C.s_w2, 520, 0, 256 + j*32, lane), acc);
#pragma unroll
  for (int nf = 0; nf < 4; ++nf)
#pragma unroll
    for (int kk = 0; kk < 2; ++kk)
      ld_sys(hfr[nf*2+kk], C.hkT_b + (size_t)(wid*64 + nf*16 + l15)*CC + kk*32 + qk);
  WAITVM(8);
#pragma unroll
  for (int j = 0; j < 4; ++j) acc = MFMA16(vb[j], frag_lds(C.s_w2, 520, 0, 384 + j*32, lane), acc);

  float bb = C.s_b2[l15];
  if (wid < 4){
#pragma unroll
    for (int r = 0; r < 4; ++r){
      int c = m0 + q*4 + r;
      __builtin_nontemporal_store(acc[r] + bb, &C.out_b[((size_t)t*CC + c)*DD + d0 + l15]);
    }
  } else {
#pragma unroll
    for (int r = 0; r < 4; ++r){
      int c = m0 + q*4 + r;
      float dvv = (acc[r] + bb - vv[r]) * (2.f/512.f);
      short db_ = f2bf(dvv);
      s_hk[c*16 + l15] = db_;
      s_t[l15*72 + c]  = db_;
    }
  }
  __syncthreads();
  if (tid < 128)
    st_sys16(C.dv_b + (size_t)tl*1024 + tid*8, *(const fragAB*)(s_hk + tid*8));
  bar_arrive(C.slots, phB, tl);
  // ---- window B: g_w2 + updates + w2T stores + b2 + s_pf prefetch ----
  {
    fragC ag[4];
#pragma unroll
    for (int i = 0; i < 4; ++i) ag[i] = zeroC();
#pragma unroll
    for (int kk = 0; kk < 2; ++kk){
      fragAB af = frag_lds(s_t, 72, 0, kk*32, lane);
#pragma unroll
      for (int nf = 0; nf < 4; ++nf)
        ag[nf] = MFMA16(af, hfr[nf*2+kk], ag[nf]);
    }
    fragAB t0, t1;
    int hr = tid >> 5;
    int c0 = (tid & 31) << 4;
    if (t + 1 < NCH){
      const u16* w2Tp = C.w2T_b + (size_t)(t&1)*W2TBUF;
      const u16* src = w2Tp + (size_t)(d0 + hr)*DD + c0;
      ld_sys(t0, src);
      ld_sys(t1, src + 8);
    }
    const float* g3 = C.aet_b + (size_t)t*3;
    float ga = g3[0], ge = g3[1], gth = g3[2];
    u16* w2Tn = C.w2T_b + (size_t)((t+1)&1)*W2TBUF;
#pragma unroll
    for (int nf = 0; nf < 4; ++nf){
      u16x4 pk;
#pragma unroll
      for (int r = 0; r < 4; ++r){
        float g  = ag[nf][r] * (1.f/64.f);
        float m_ = ge*mw2f[nf*4+r] - gth*g;
        float w_ = (1.f-ga)*w2f[nf*4+r] + m_;
        mw2f[nf*4+r] = m_; w2f[nf*4+r] = w_;
        short wb = f2bf(w_);
        C.s_w2[(q*4+r)*520 + wid*64 + nf*16 + l15] = wb;
        pk[r] = wb;
      }
      st_sys8(w2Tn + (size_t)(wid*64 + nf*16 + l15)*DD + d0 + q*4, pk);
    }
    if (tid < 16){
      const fragAB* row = (const fragAB*)(s_t + tid*72);
      float s = 0.f;
#pragma unroll
      for (int j = 0; j < 8; ++j){
        fragAB v = row[j];
#pragma unroll
        for (int i = 0; i < 8; ++i) s += bf2f(v[i]);
      }
      float gb = s * (1.f/64.f);
      float m_ = ge*C.s_mb2[tid] - gth*gb;
      float bn = (1.f-ga)*C.s_b2[tid] + m_;
      C.s_mb2[tid] = m_; C.s_b2[tid] = bn;
    }
    if (t + 1 < NCH){
      WAITVM(0);
      *(fragAB*)(C.s_pf + hr*520 + c0)     = t0;
      *(fragAB*)(C.s_pf + hr*520 + c0 + 8) = t1;
    }
  }
}

// ---------------- persistent fused scan: dual-batch interleave ----------------
__global__ __launch_bounds__(512, 1) void k_scan(
    const u16* __restrict__ Qb, const u16* __restrict__ Kb, const u16* __restrict__ KTg,
    const float* __restrict__ V, const float* __restrict__ aet,
    const float* __restrict__ iw1, const float* __restrict__ ib1,
    const float* __restrict__ iw2, const float* __restrict__ ib2,
    u16* __restrict__ hkb, u16* __restrict__ hqs, u16* __restrict__ hkT,
    u16* __restrict__ dvpb, u16* __restrict__ w2Tb,
    float* __restrict__ out, unsigned* __restrict__ barb)
{
  extern __shared__ __align__(16) char smem_raw[];
  short* sp = (short*)smem_raw;
  short* s_w1a = sp;               sp += 16*520;
  short* s_w2a = sp;               sp += 16*520;
  short* s_pfa = sp;               sp += 16*520;
  short* s_w1b = sp;               sp += 16*520;
  short* s_w2b = sp;               sp += 16*520;
  short* s_pfb = sp;               sp += 16*520;
  short* s_t   = sp;               sp += 16*72;
  short* s_hk  = sp;               sp += 64*16;
  short* s_hq  = sp;               sp += 64*16;
  float* fb = (float*)sp;
  float (*s_part)[17] = (float(*)[17])fb;  fb += 64*17;
  float* s_b1a = fb;  fb += 16;  float* s_mb1a = fb; fb += 16;
  float* s_b2a = fb;  fb += 16;  float* s_mb2a = fb; fb += 16;
  float* s_b1b = fb;  fb += 16;  float* s_mb1b = fb; fb += 16;
  float* s_b2b = fb;  fb += 16;  float* s_mb2b = fb; fb += 16;

  const int tid  = threadIdx.x;
  const int lane = tid & 63;
  const int wid  = tid >> 6;
  const int q    = lane >> 4;
  const int l15  = lane & 15;
  const int qk   = q << 3;
  const int g    = blockIdx.x & 1;
  const int tl   = blockIdx.x >> 1;
  const int h0   = tl * 16;
  const int b0   = g*2, b1 = g*2 + 1;
  const size_t W2TBUF = (size_t)BB*DD*LWW;

  BCtx C0, C1;
  {
    C0.Kball = Kb + (size_t)b0*SS*DD;  C1.Kball = Kb + (size_t)b1*SS*DD;
    C0.Qball = Qb + (size_t)b0*SS*DD;  C1.Qball = Qb + (size_t)b1*SS*DD;
    C0.KTbat = KTg + (size_t)b0*DD*SS; C1.KTbat = KTg + (size_t)b1*DD*SS;
    C0.hk_b  = hkb + (size_t)b0*CC*LWW;  C1.hk_b  = hkb + (size_t)b1*CC*LWW;
    C0.hq_b  = hqs + (size_t)b0*CC*LWW;  C1.hq_b  = hqs + (size_t)b1*CC*LWW;
    C0.hkT_b = hkT + (size_t)b0*LWW*CC;  C1.hkT_b = hkT + (size_t)b1*LWW*CC;
    C0.dv_b  = dvpb + (size_t)b0*CC*DD;  C1.dv_b  = dvpb + (size_t)b1*CC*DD;
    C0.w2T_b = w2Tb + (size_t)b0*DD*LWW; C1.w2T_b = w2Tb + (size_t)b1*DD*LWW;
    C0.V_b   = V + (size_t)b0*SS*DD;     C1.V_b   = V + (size_t)b1*SS*DD;
    C0.aet_b = aet + (size_t)b0*NCH*3;   C1.aet_b = aet + (size_t)b1*NCH*3;
    C0.out_b = out + (size_t)b0*SS*DD;   C1.out_b = out + (size_t)b1*SS*DD;
    C0.slots = barb + (size_t)b0*1024;   C1.slots = barb + (size_t)b1*1024;
    C0.s_w1 = s_w1a; C0.s_w2 = s_w2a; C0.s_pf = s_pfa;
    C1.s_w1 = s_w1b; C1.s_w2 = s_w2b; C1.s_pf = s_pfb;
    C0.s_b1 = s_b1a; C0.s_mb1 = s_mb1a; C0.s_b2 = s_b2a; C0.s_mb2 = s_mb2a;
    C1.s_b1 = s_b1b; C1.s_mb1 = s_mb1b; C1.s_b2 = s_b2b; C1.s_mb2 = s_mb2b;
  }

  float w1f0[16], mw1f0[16], w2f0[16], mw2f0[16], actr0[4];
  float w1f1[16], mw1f1[16], w2f1[16], mw2f1[16], actr1[4];

  do_init(C0, iw1, ib1, iw2, ib2, tid, wid, q, l15, h0, w1f0, mw1f0, w2f0, mw2f0, actr0);
  do_init(C1, iw1, ib1, iw2, ib2, tid, wid, q, l15, h0, w1f1, mw1f1, w2f1, mw2f1, actr1);
  WAITVM(0);
  __syncthreads();

  for (int t = 0; t < NCH; ++t){
    unsigned phA = 2u*t + 1u, phB = 2u*t + 2u;
    do_phaseA(C0, t, tid, lane, wid, q, l15, qk, tl, h0,
              w1f0, mw1f0, actr0, s_t, s_hk, s_hq, s_part, phA);
    if (t > 0) bar_wait(C1.slots, 2u*t);           // waitB(b1, t-1)
    do_phaseA(C1, t, tid, lane, wid, q, l15, qk, tl, h0,
              w1f1, mw1f1, actr1, s_t, s_hk, s_hq, s_part, phA);
    bar_wait(C0.slots, phA);                       // waitA(b0)
    do_phaseB(C0, t, tid, lane, wid, q, l15, qk, tl, h0,
              w2f0, mw2f0, s_t, s_hk, phB, W2TBUF);
    bar_wait(C1.slots, phA);                       // waitA(b1)
    do_phaseB(C1, t, tid, lane, wid, q, l15, qk, tl, h0,
              w2f1, mw2f1, s_t, s_hk, phB, W2TBUF);
    bar_wait(C0.slots, phB);                       // waitB(b0)
  }
  WAITVM(0);
}

extern "C" void kernel_launch(void* const* d_in, const int* in_sizes, int n_in,
                              void* d_out, int out_size, void* d_ws, size_t ws_size,
                              hipStream_t stream){
  const float* x   = (const float*)d_in[0];
  const float* Wq  = (const float*)d_in[1];
  const float* Wk  = (const float*)d_in[2];
  const float* Wv  = (const float*)d_in[3];
  const float* iw1 = (const float*)d_in[4];
  const float* ib1 = (const float*)d_in[5];
  const float* iw2 = (const float*)d_in[6];
  const float* ib2 = (const float*)d_in[7];
  const float* aw  = (const float*)d_in[8];
  const float* ab  = (const float*)d_in[9];
  const float* ew  = (const float*)d_in[10];
  const float* eb  = (const float*)d_in[11];
  const float* tw  = (const float*)d_in[12];
  const float* tb  = (const float*)d_in[13];
  float* out = (float*)d_out;

  float* fw = (float*)d_ws;
  float* V    = fw;  fw += (size_t)BB*SS*DD;
  float* aet  = fw;  fw += (size_t)BB*NCH*3 + 64;
  unsigned* bar = (unsigned*)fw; fw += 4096;
  u16* xb   = (u16*)fw;                       // aliased as KTg after k_proj
  u16* Wc   = xb   + (size_t)BB*SS*DD;
  u16* Qb   = Wc   + (size_t)3*DD*DD;
  u16* Kb   = Qb   + (size_t)BB*SS*DD;
  u16* hkb  = Kb   + (size_t)BB*SS*DD;
  u16* hqs  = hkb  + (size_t)BB*CC*LWW;
  u16* hkT  = hqs  + (size_t)BB*CC*LWW;
  u16* dvpb = hkT  + (size_t)BB*LWW*CC;
  u16* w2Tb = dvpb + (size_t)BB*CC*DD;        // 2 buffers of BB*DD*LWW
  u16* KTg  = xb;

  k_cvt  <<<8960, 256, 0, stream>>>(x, Wq, Wk, Wv, xb, Wc, bar);
  k_proj <<<3072, 256, 0, stream>>>(xb, Wc, Qb, Kb, V);
  k_norm <<<8192, 256, 0, stream>>>(Qb, Kb);
  k_trans<<<2048, 256, 0, stream>>>(Kb, KTg);
  k_gates<<<256,  256, 0, stream>>>(x, aw, ab, ew, eb, tw, tb, aet);
  k_scan <<<64,   512, SCAN_SMEM, stream>>>(Qb, Kb, KTg, V, aet, iw1, ib1, iw2, ib2,
                                            hkb, hqs, hkT, dvpb, w2Tb, out, bar);
}

// Round 11
// 1326.170 us; speedup vs baseline: 2.7611x; 2.7611x over previous
//
#include <hip/hip_runtime.h>
#include <hip/hip_bf16.h>

#define BB 4
#define SS 4096
#define DD 512
#define LWW 512
#define CC 64
#define NCH 64

typedef unsigned short u16;
using fragAB = __attribute__((ext_vector_type(8))) short;
using fragC  = __attribute__((ext_vector_type(4))) float;
using u16x4  = __attribute__((ext_vector_type(4))) short;

__device__ __forceinline__ short f2bf(float f){
  unsigned u = __float_as_uint(f);
  u = (u + 0x7FFFu + ((u >> 16) & 1u)) >> 16;
  return (short)u;
}
__device__ __forceinline__ float bf2f(short s){
  return __uint_as_float(((unsigned)(u16)s) << 16);
}
__device__ __forceinline__ fragC zeroC(){ fragC z = {0.f,0.f,0.f,0.f}; return z; }

__device__ __forceinline__ fragAB frag_bf16g(const u16* __restrict__ base, int ld, int r0, int k0, int lane){
  return *(const fragAB*)(base + (size_t)(r0 + (lane & 15)) * ld + k0 + ((lane >> 4) << 3));
}
__device__ __forceinline__ fragAB frag_lds(const short* base, int ld, int r0, int k0, int lane){
  return *(const fragAB*)(base + (r0 + (lane & 15)) * ld + k0 + ((lane >> 4) << 3));
}
#define MFMA16(a,b,c) __builtin_amdgcn_mfma_f32_16x16x32_bf16(a,b,c,0,0,0)

// ---- system-coherent (Infinity-Cache) access ----
__device__ __forceinline__ void ld_sys(fragAB& r, const u16* p){
  asm volatile("global_load_dwordx4 %0, %1, off sc0 sc1" : "=v"(r) : "v"(p) : "memory");
}
__device__ __forceinline__ void st_sys8(u16* p, u16x4 v){
  asm volatile("global_store_dwordx2 %0, %1, off sc0 sc1" :: "v"(p), "v"(v) : "memory");
}
__device__ __forceinline__ void st_sys16(u16* p, fragAB v){
  asm volatile("global_store_dwordx4 %0, %1, off sc0 sc1" :: "v"(p), "v"(v) : "memory");
}
#define WAITVM(N) do { asm volatile("s_waitcnt vmcnt(" #N ")" ::: "memory"); \
                       __builtin_amdgcn_sched_barrier(0); } while (0)

// tiled exchange layout [k/16][64 c][16]
__device__ __forceinline__ const u16* taddr(const u16* base, int c, int kq){
  return base + (((size_t)((kq >> 4)*64 + c)) << 4) + (kq & 15);
}

// ---------------- split distributed per-batch barrier ----------------
__device__ __forceinline__ void bar_arrive(unsigned* slots, unsigned phase, int tl){
  asm volatile("s_waitcnt vmcnt(0)" ::: "memory");
  __builtin_amdgcn_sched_barrier(0);
  __syncthreads();
  if (threadIdx.x == 0)
    __hip_atomic_store(slots + (size_t)tl*32, phase, __ATOMIC_RELAXED, __HIP_MEMORY_SCOPE_AGENT);
}
__device__ __forceinline__ void bar_wait(unsigned* slots, unsigned phase){
  if (threadIdx.x < 64){
    bool mine = threadIdx.x < 32;
    unsigned* sp = slots + (size_t)(threadIdx.x & 31)*32;
    for (;;){
      unsigned v = mine ? __hip_atomic_load(sp, __ATOMIC_RELAXED, __HIP_MEMORY_SCOPE_AGENT) : phase;
      if (__all((int)(v >= phase))) break;
      __builtin_amdgcn_s_sleep(1);
    }
  }
  __syncthreads();
}

// ---------------- fp32 -> bf16 conversions + bar zero ----------------
__global__ __launch_bounds__(256) void k_cvt(const float* __restrict__ x,
    const float* __restrict__ Wq, const float* __restrict__ Wk, const float* __restrict__ Wv,
    u16* __restrict__ xb, u16* __restrict__ Wc, unsigned* __restrict__ bar){
  size_t i = (size_t)blockIdx.x * 256 + threadIdx.x;
  if (blockIdx.x == 0){
    for (int z = threadIdx.x; z < 4096; z += 256) bar[z] = 0u;
  }
  const size_t NX4 = (size_t)BB*SS*DD/4;
  const size_t NW4 = (size_t)DD*DD/4;
  if (i < NX4){
    float4 v = ((const float4*)x)[i];
    u16x4 o = { f2bf(v.x), f2bf(v.y), f2bf(v.z), f2bf(v.w) };
    *(u16x4*)(xb + 4*i) = o;
  } else if (i < NX4 + 3*NW4){
    size_t j = i - NX4;
    const float* src = (j < NW4) ? Wq : (j < 2*NW4) ? Wk : Wv;
    size_t jj = j % NW4;
    float4 v = ((const float4*)src)[jj];
    u16x4 o = { f2bf(v.x), f2bf(v.y), f2bf(v.z), f2bf(v.w) };
    *(u16x4*)(Wc + 4*j) = o;
  }
}

// ---------------- Q,K,V projections ----------------
__global__ __launch_bounds__(256) void k_proj(const u16* __restrict__ xb,
    const u16* __restrict__ Wc,
    u16* __restrict__ Qb, u16* __restrict__ Kb, float* __restrict__ V){
  int mt = blockIdx.x / 12, nt = blockIdx.x % 12;
  int lane = threadIdx.x & 63, wid = threadIdx.x >> 6;
  int m0 = mt * 64 + wid * 16;
  const u16* Bp = Wc + (size_t)nt * 128 * DD;
  fragC acc[8];
#pragma unroll
  for (int i = 0; i < 8; ++i) acc[i] = zeroC();
  for (int k0 = 0; k0 < DD; k0 += 32){
    fragAB a = frag_bf16g(xb, DD, m0, k0, lane);
#pragma unroll
    for (int nf = 0; nf < 8; ++nf)
      acc[nf] = MFMA16(a, frag_bf16g(Bp, DD, nf*16, k0, lane), acc[nf]);
  }
#pragma unroll
  for (int nf = 0; nf < 8; ++nf){
#pragma unroll
    for (int r = 0; r < 4; ++r){
      int m = m0 + ((lane >> 4) << 2) + r;
      int col = nt*128 + nf*16 + (lane & 15);
      float v = acc[nf][r];
      if (nt < 4)      Qb[(size_t)m*DD + col]        = (u16)f2bf(v);
      else if (nt < 8) Kb[(size_t)m*DD + col - 512]  = (u16)f2bf(v);
      else             V [(size_t)m*DD + col - 1024] = v;
    }
  }
}

// ---------------- l2-normalize Q,K rows ----------------
__global__ __launch_bounds__(256) void k_norm(u16* __restrict__ Qb, u16* __restrict__ Kb){
  int idx = blockIdx.x * 4 + (threadIdx.x >> 6);
  int lane = threadIdx.x & 63;
  u16* p = (idx < BB*SS ? Qb + (size_t)idx * DD
                        : Kb + (size_t)(idx - BB*SS) * DD) + lane * 8;
  fragAB v = *(const fragAB*)p;
  float f[8]; float s = 0.f;
#pragma unroll
  for (int i = 0; i < 8; ++i){ f[i] = bf2f(v[i]); s += f[i]*f[i]; }
#pragma unroll
  for (int o = 32; o > 0; o >>= 1) s += __shfl_xor(s, o, 64);
  float inv = 1.f / fmaxf(sqrtf(s), 1e-12f);
  fragAB o8;
#pragma unroll
  for (int i = 0; i < 8; ++i) o8[i] = f2bf(f[i] * inv);
  *(fragAB*)p = o8;
}

// ---------------- transpose K ----------------
__global__ __launch_bounds__(256) void k_trans(const u16* __restrict__ Kb, u16* __restrict__ KT){
  __shared__ short tile[64][68];
  int blk = blockIdx.x;
  int b = blk >> 9, rem = blk & 511;
  int st = rem >> 3, dt = rem & 7;
  int s0 = st*64, d0 = dt*64;
  int sr = threadIdx.x & 63, q = threadIdx.x >> 6;
  const u16* src = Kb + ((size_t)b*SS + s0 + sr)*DD + d0 + q*16;
  fragAB v0 = *(const fragAB*)src;
  fragAB v1 = *(const fragAB*)(src + 8);
#pragma unroll
  for (int i = 0; i < 8; ++i){ tile[sr][q*16+i] = v0[i]; tile[sr][q*16+8+i] = v1[i]; }
  __syncthreads();
  fragAB o0, o1;
#pragma unroll
  for (int i = 0; i < 8; ++i){ o0[i] = tile[q*16+i][sr]; o1[i] = tile[q*16+8+i][sr]; }
  u16* dst = KT + ((size_t)b*DD + d0 + sr)*SS + s0 + q*16;
  *(fragAB*)dst = o0;
  *(fragAB*)(dst + 8) = o1;
}

// ---------------- gates ----------------
__global__ __launch_bounds__(256) void k_gates(const float* __restrict__ x,
    const float* __restrict__ aw, const float* __restrict__ ab,
    const float* __restrict__ ew, const float* __restrict__ eb,
    const float* __restrict__ tw, const float* __restrict__ tb,
    float* __restrict__ aet){
  __shared__ float part[64][4][3];
  __shared__ float rowsig[64][3];
  int b = blockIdx.x >> 6, t = blockIdx.x & 63;
  int tid = threadIdx.x;
  int r = tid >> 2, p = tid & 3;
  const float4* xp = (const float4*)(x + ((size_t)b*SS + (size_t)t*CC + r) * DD + p * 128);
  const float4* a4 = (const float4*)(aw + p*128);
  const float4* e4 = (const float4*)(ew + p*128);
  const float4* t4 = (const float4*)(tw + p*128);
  float s0 = 0.f, s1 = 0.f, s2 = 0.f;
  for (int i = 0; i < 32; ++i){
    float4 xv = xp[i], av = a4[i], ev = e4[i], tv = t4[i];
    s0 += xv.x*av.x + xv.y*av.y + xv.z*av.z + xv.w*av.w;
    s1 += xv.x*ev.x + xv.y*ev.y + xv.z*ev.z + xv.w*ev.w;
    s2 += xv.x*tv.x + xv.y*tv.y + xv.z*tv.z + xv.w*tv.w;
  }
  part[r][p][0] = s0; part[r][p][1] = s1; part[r][p][2] = s2;
  __syncthreads();
  if (tid < 64){
    float a_ = part[tid][0][0]+part[tid][1][0]+part[tid][2][0]+part[tid][3][0] + ab[0];
    float e_ = part[tid][0][1]+part[tid][1][1]+part[tid][2][1]+part[tid][3][1] + eb[0];
    float t_ = part[tid][0][2]+part[tid][1][2]+part[tid][2][2]+part[tid][3][2] + tb[0];
    rowsig[tid][0] = 1.f/(1.f+expf(-a_));
    rowsig[tid][1] = 1.f/(1.f+expf(-e_));
    rowsig[tid][2] = 1.f/(1.f+expf(-t_));
  }
  __syncthreads();
  if (tid < 3){
    float s = 0.f;
    for (int i = 0; i < 64; ++i) s += rowsig[i][tid];
    aet[((size_t)b*NCH + t)*3 + tid] = s * (1.f/64.f);
  }
}

// ---------------- persistent fused scan (R9 + dh-first issue + V window prefetch) ----------------
__global__ __launch_bounds__(512, 2) void k_scan(
    const u16* __restrict__ Qb, const u16* __restrict__ Kb, const u16* __restrict__ KTg,
    const float* __restrict__ V, const float* __restrict__ aet,
    const float* __restrict__ iw1, const float* __restrict__ ib1,
    const float* __restrict__ iw2, const float* __restrict__ ib2,
    u16* __restrict__ hkb, u16* __restrict__ hqs, u16* __restrict__ hkT,
    u16* __restrict__ dvpb, u16* __restrict__ w2Tb,
    float* __restrict__ out, unsigned* __restrict__ barb)
{
  __shared__ __align__(16) short s_w1[16*520];
  __shared__ __align__(16) short s_w2[16*520];
  __shared__ __align__(16) short s_pf[16*520];   // prefetched w2T tile for next dh
  __shared__ __align__(16) short s_t[16*72];
  __shared__ __align__(16) short s_hk[64*16];    // phase A hk staging / phase B dv staging
  __shared__ __align__(16) short s_hq[64*16];    // phase A hq staging
  __shared__ float s_part[64][17];               // dh K-split partials
  __shared__ float s_b1[16], s_mb1[16], s_b2[16], s_mb2[16];

  const int tid  = threadIdx.x;
  const int lane = tid & 63;
  const int wid  = tid >> 6;
  const int q    = lane >> 4;
  const int l15  = lane & 15;
  const int qk   = q << 3;
  const int b    = (blockIdx.x & 7) >> 1;
  const int tl   = ((blockIdx.x >> 3) << 1) | (blockIdx.x & 1);
  const int h0   = tl * 16;
  const int d0   = tl * 16;
  unsigned* slots = barb + (size_t)b * 1024;
  unsigned  ph   = 0;

  const u16* Kball = Kb  + (size_t)b*SS*DD;
  const u16* Qball = Qb  + (size_t)b*SS*DD;
  const u16* KTbat = KTg + (size_t)b*DD*SS;
  u16* hk_b  = hkb  + (size_t)b*CC*LWW;
  u16* hq_b  = hqs  + (size_t)b*CC*LWW;
  u16* hkT_b = hkT  + (size_t)b*LWW*CC;
  u16* dv_b  = dvpb + (size_t)b*CC*DD;
  const size_t W2TBUF = (size_t)BB*DD*LWW;

  float w1f[16], mw1f[16], w2f[16], mw2f[16], actr[4];

  // ---- preamble: init state; initial w2T -> buf[0] ----
  {
    u16* w2T0 = w2Tb + (size_t)b*DD*LWW;
#pragma unroll
    for (int nf = 0; nf < 4; ++nf){
      u16x4 pk;
#pragma unroll
      for (int r = 0; r < 4; ++r){
        int hr = q*4 + r;
        int dcol = wid*64 + nf*16 + l15;
        float a = iw1[(size_t)(h0 + hr)*DD + dcol];
        w1f[nf*4+r] = a; mw1f[nf*4+r] = 0.f;
        s_w1[hr*520 + dcol] = f2bf(a);
        float c = iw2[(size_t)(d0 + hr)*LWW + dcol];
        w2f[nf*4+r] = c; mw2f[nf*4+r] = 0.f;
        s_w2[hr*520 + dcol] = f2bf(c);
        pk[r] = f2bf(c);
      }
      st_sys8(w2T0 + (size_t)(wid*64 + nf*16 + l15)*DD + d0 + q*4, pk);
    }
    if (tid < 16){
      s_b1[tid] = ib1[h0 + tid]; s_mb1[tid] = 0.f;
      s_b2[tid] = ib2[d0 + tid]; s_mb2[tid] = 0.f;
    }
#pragma unroll
    for (int r = 0; r < 4; ++r) actr[r] = 0.f;
    WAITVM(0);
    __syncthreads();
  }

  for (int t = 0; t < NCH; ++t){
    float vv[4];
    // ======== PHASE A ========
    if (t > 0){
      fragAB kfr[8];
      // dh K-split: all 8 waves; issue IC loads FIRST (slow RTT starts earliest)
      {
        const int cst = (wid & 3) * 16;
        const int kh  = (wid >> 2) * 256;
        fragAB fa[8];
        fragC a0 = zeroC();
#pragma unroll
        for (int j = 0; j < 8; ++j) ld_sys(fa[j], taddr(dv_b, cst + l15, kh + j*32 + qk));
        // g_w1 B-fragments: cached KT(t-1) — L2 hits ride inside the dh RTT
        {
          const u16* KTm = KTbat + (size_t)(t-1)*CC;
#pragma unroll
          for (int nf = 0; nf < 4; ++nf)
#pragma unroll
            for (int kk = 0; kk < 2; ++kk)
              kfr[nf*2+kk] = frag_bf16g(KTm, SS, wid*64 + nf*16, kk*32, lane);
        }
        WAITVM(12);   // >= 4 oldest (dh) retired; kfr newer, still in flight
#pragma unroll
        for (int j = 0; j < 4; ++j) a0 = MFMA16(fa[j], frag_lds(s_pf, 520, 0, kh + j*32, lane), a0);
        WAITVM(8);    // all 8 dh retired
#pragma unroll
        for (int j = 4; j < 8; ++j) a0 = MFMA16(fa[j], frag_lds(s_pf, 520, 0, kh + j*32, lane), a0);
        if (wid >= 4){
#pragma unroll
          for (int r = 0; r < 4; ++r) s_part[cst + q*4 + r][l15] = a0[r];
        }
        __syncthreads();
        if (wid < 4){
#pragma unroll
          for (int r = 0; r < 4; ++r){
            float v = (a0[r] + s_part[cst + q*4 + r][l15]) * actr[r];
            s_t[l15*72 + cst + q*4 + r] = f2bf(v);
          }
        }
      }
      __syncthreads();
      { // g_w1 [16 h][512 d], K = 64 c
        fragC ag[4];
#pragma unroll
        for (int i = 0; i < 4; ++i) ag[i] = zeroC();
#pragma unroll
        for (int kk = 0; kk < 2; ++kk){
          fragAB af = frag_lds(s_t, 72, 0, kk*32, lane);
#pragma unroll
          for (int nf = 0; nf < 4; ++nf)
            ag[nf] = MFMA16(af, kfr[nf*2+kk], ag[nf]);
        }
        const float* g3 = aet + ((size_t)b*NCH + (t-1)) * 3;
        float ga = g3[0], ge = g3[1], gth = g3[2];
#pragma unroll
        for (int nf = 0; nf < 4; ++nf)
#pragma unroll
          for (int r = 0; r < 4; ++r){
            float g  = ag[nf][r] * (1.f/64.f);
            float m_ = ge*mw1f[nf*4+r] - gth*g;
            float w_ = (1.f-ga)*w1f[nf*4+r] + m_;
            mw1f[nf*4+r] = m_; w1f[nf*4+r] = w_;
            s_w1[(q*4+r)*520 + wid*64 + nf*16 + l15] = f2bf(w_);
          }
        if (tid < 16){
          const fragAB* row = (const fragAB*)(s_t + tid*72);
          float s = 0.f;
#pragma unroll
          for (int j = 0; j < 8; ++j){
            fragAB v = row[j];
#pragma unroll
            for (int i = 0; i < 8; ++i) s += bf2f(v[i]);
          }
          float gb = s * (1.f/64.f);
          float m_ = ge*s_mb1[tid] - gth*gb;
          float bn = (1.f-ga)*s_b1[tid] + m_;
          s_mb1[tid] = m_; s_b1[tid] = bn;
        }
      }
    }
    __syncthreads();
    // pre (waves 0-3, K) & hq (waves 4-7, Q): cached A + LDS B; stage to LDS
    {
      const u16* Ac = (wid < 4 ? Kball : Qball) + (size_t)t*CC*DD;
      int m0 = (wid & 3) * 16;
      fragC acc = zeroC();
      for (int k0 = 0; k0 < DD; k0 += 32)
        acc = MFMA16(frag_bf16g(Ac, DD, m0, k0, lane),
                     frag_lds(s_w1, 520, 0, k0, lane), acc);
      float bb = s_b1[l15];
      if (wid < 4){
#pragma unroll
        for (int r = 0; r < 4; ++r){
          int c = m0 + q*4 + r;
          float pre = acc[r] + bb;
          float sg  = 1.f/(1.f+expf(-pre));
          float hkv = pre * sg;
          actr[r]   = sg * (1.f + pre * (1.f - sg));
          short hb  = f2bf(hkv);
          s_hk[c*16 + l15] = hb;
          s_t[l15*72 + c]  = hb;        // hkT staging [16 h][c]
        }
      } else {
#pragma unroll
        for (int r = 0; r < 4; ++r){
          int c = m0 + q*4 + r;
          float hqv = acc[r] + bb;
          float s2  = 1.f/(1.f+expf(-hqv));
          s_hq[c*16 + l15] = f2bf(hqv * s2);
        }
      }
    }
    __syncthreads();
    // coalesced burst stores: hk, hq (tiled) + hkT (row-contiguous lines)
    if (tid < 128){
      st_sys16(hk_b + (size_t)tl*1024 + tid*8, *(const fragAB*)(s_hk + tid*8));
    } else if (tid < 256){
      int i = tid - 128;
      st_sys16(hq_b + (size_t)tl*1024 + i*8, *(const fragAB*)(s_hq + i*8));
    } else if (tid < 384){
      int i = tid - 256;
      int row = i >> 3, seg = i & 7;
      st_sys16(hkT_b + (size_t)(h0 + row)*CC + seg*8, *(const fragAB*)(s_t + row*72 + seg*8));
    }
    ph++; bar_arrive(slots, ph, tl);
    // ---- window A: V prefetch (cached; RTT hides under barrier wait) ----
    if (wid >= 4){
      int m0 = (wid & 3) * 16;
#pragma unroll
      for (int r = 0; r < 4; ++r)
        vv[r] = V[((size_t)b*SS + (size_t)t*CC + m0 + q*4 + r)*DD + d0 + l15];
    }
    bar_wait(slots, ph);

    // ======== PHASE B ========
    {
      const u16* Ah = (wid < 4) ? hq_b : hk_b;
      int m0 = (wid & 3) * 16;
      fragC acc = zeroC();
      fragAB va[4], vb[4], hfr[8];
#pragma unroll
      for (int j = 0; j < 4; ++j) ld_sys(va[j], taddr(Ah, m0 + l15, j*32 + qk));
#pragma unroll
      for (int j = 0; j < 4; ++j) ld_sys(vb[j], taddr(Ah, m0 + l15, 128 + j*32 + qk));
      WAITVM(4);
#pragma unroll
      for (int j = 0; j < 4; ++j) acc = MFMA16(va[j], frag_lds(s_w2, 520, 0, j*32, lane), acc);
#pragma unroll
      for (int j = 0; j < 4; ++j) ld_sys(va[j], taddr(Ah, m0 + l15, 256 + j*32 + qk));
      WAITVM(4);
#pragma unroll
      for (int j = 0; j < 4; ++j) acc = MFMA16(vb[j], frag_lds(s_w2, 520, 0, 128 + j*32, lane), acc);
#pragma unroll
      for (int j = 0; j < 4; ++j) ld_sys(vb[j], taddr(Ah, m0 + l15, 384 + j*32 + qk));
      WAITVM(4);
#pragma unroll
      for (int j = 0; j < 4; ++j) acc = MFMA16(va[j], frag_lds(s_w2, 520, 0, 256 + j*32, lane), acc);
#pragma unroll
      for (int nf = 0; nf < 4; ++nf)
#pragma unroll
        for (int kk = 0; kk < 2; ++kk)
          ld_sys(hfr[nf*2+kk], hkT_b + (size_t)(wid*64 + nf*16 + l15)*CC + kk*32 + qk);
      WAITVM(8);
#pragma unroll
      for (int j = 0; j < 4; ++j) acc = MFMA16(vb[j], frag_lds(s_w2, 520, 0, 384 + j*32, lane), acc);

      float bb = s_b2[l15];
      if (wid < 4){
#pragma unroll
        for (int r = 0; r < 4; ++r){
          int c = m0 + q*4 + r;
          __builtin_nontemporal_store(acc[r] + bb,
            &out[((size_t)b*SS + (size_t)t*CC + c)*DD + d0 + l15]);
        }
      } else {
#pragma unroll
        for (int r = 0; r < 4; ++r){
          int c = m0 + q*4 + r;
          float dvv = (acc[r] + bb - vv[r]) * (2.f/512.f);
          short db_ = f2bf(dvv);
          s_hk[c*16 + l15] = db_;       // dv staging
          s_t[l15*72 + c]  = db_;       // dvT for g_w2 A-operand
        }
      }
      __syncthreads();
      // dv burst store (contiguous own tile)
      if (tid < 128)
        st_sys16(dv_b + (size_t)tl*1024 + tid*8, *(const fragAB*)(s_hk + tid*8));
      ph++; bar_arrive(slots, ph, tl);
      // ---- window B: g_w2 + updates + w2T stores + b2 + s_pf prefetch ----
      {
        fragC ag[4];
#pragma unroll
        for (int i = 0; i < 4; ++i) ag[i] = zeroC();
#pragma unroll
        for (int kk = 0; kk < 2; ++kk){
          fragAB af = frag_lds(s_t, 72, 0, kk*32, lane);
#pragma unroll
          for (int nf = 0; nf < 4; ++nf)
            ag[nf] = MFMA16(af, hfr[nf*2+kk], ag[nf]);
        }
        // s_pf prefetch: issue loads early (hide RTT under update VALU)
        fragAB t0, t1;
        int hr = tid >> 5;
        int c0 = (tid & 31) << 4;
        if (t + 1 < NCH){
          const u16* w2Tp = w2Tb + (size_t)(t&1)*W2TBUF + (size_t)b*DD*LWW;
          const u16* src = w2Tp + (size_t)(h0 + hr)*DD + c0;
          ld_sys(t0, src);
          ld_sys(t1, src + 8);
        }
        const float* g3 = aet + ((size_t)b*NCH + t) * 3;
        float ga = g3[0], ge = g3[1], gth = g3[2];
        u16* w2Tn = w2Tb + (size_t)((t+1)&1)*W2TBUF + (size_t)b*DD*LWW;
#pragma unroll
        for (int nf = 0; nf < 4; ++nf){
          u16x4 pk;
#pragma unroll
          for (int r = 0; r < 4; ++r){
            float g  = ag[nf][r] * (1.f/64.f);
            float m_ = ge*mw2f[nf*4+r] - gth*g;
            float w_ = (1.f-ga)*w2f[nf*4+r] + m_;
            mw2f[nf*4+r] = m_; w2f[nf*4+r] = w_;
            short wb = f2bf(w_);
            s_w2[(q*4+r)*520 + wid*64 + nf*16 + l15] = wb;
            pk[r] = wb;
          }
          st_sys8(w2Tn + (size_t)(wid*64 + nf*16 + l15)*DD + d0 + q*4, pk);
        }
        if (tid < 16){
          const fragAB* row = (const fragAB*)(s_t + tid*72);
          float s = 0.f;
#pragma unroll
          for (int j = 0; j < 8; ++j){
            fragAB v = row[j];
#pragma unroll
            for (int i = 0; i < 8; ++i) s += bf2f(v[i]);
          }
          float gb = s * (1.f/64.f);
          float m_ = ge*s_mb2[tid] - gth*gb;
          float bn = (1.f-ga)*s_b2[tid] + m_;
          s_mb2[tid] = m_; s_b2[tid] = bn;
        }
        if (t + 1 < NCH){
          WAITVM(0);   // drains s_pf loads AND this chunk's w2T stores (ordering guarantee)
          *(fragAB*)(s_pf + hr*520 + c0)     = t0;
          *(fragAB*)(s_pf + hr*520 + c0 + 8) = t1;
        }
      }
      bar_wait(slots, ph);
    }
  }
}

extern "C" void kernel_launch(void* const* d_in, const int* in_sizes, int n_in,
                              void* d_out, int out_size, void* d_ws, size_t ws_size,
                              hipStream_t stream){
  const float* x   = (const float*)d_in[0];
  const float* Wq  = (const float*)d_in[1];
  const float* Wk  = (const float*)d_in[2];
  const float* Wv  = (const float*)d_in[3];
  const float* iw1 = (const float*)d_in[4];
  const float* ib1 = (const float*)d_in[5];
  const float* iw2 = (const float*)d_in[6];
  const float* ib2 = (const float*)d_in[7];
  const float* aw  = (const float*)d_in[8];
  const float* ab  = (const float*)d_in[9];
  const float* ew  = (const float*)d_in[10];
  const float* eb  = (const float*)d_in[11];
  const float* tw  = (const float*)d_in[12];
  const float* tb  = (const float*)d_in[13];
  float* out = (float*)d_out;

  float* fw = (float*)d_ws;
  float* V    = fw;  fw += (size_t)BB*SS*DD;
  float* aet  = fw;  fw += (size_t)BB*NCH*3 + 64;
  unsigned* bar = (unsigned*)fw; fw += 4096;
  u16* xb   = (u16*)fw;                       // aliased as KTg after k_proj
  u16* Wc   = xb   + (size_t)BB*SS*DD;
  u16* Qb   = Wc   + (size_t)3*DD*DD;
  u16* Kb   = Qb   + (size_t)BB*SS*DD;
  u16* hkb  = Kb   + (size_t)BB*SS*DD;
  u16* hqs  = hkb  + (size_t)BB*CC*LWW;
  u16* hkT  = hqs  + (size_t)BB*CC*LWW;
  u16* dvpb = hkT  + (size_t)BB*LWW*CC;
  u16* w2Tb = dvpb + (size_t)BB*CC*DD;        // 2 buffers of BB*DD*LWW
  u16* KTg  = xb;

  k_cvt  <<<8960, 256, 0, stream>>>(x, Wq, Wk, Wv, xb, Wc, bar);
  k_proj <<<3072, 256, 0, stream>>>(xb, Wc, Qb, Kb, V);
  k_norm <<<8192, 256, 0, stream>>>(Qb, Kb);
  k_trans<<<2048, 256, 0, stream>>>(Kb, KTg);
  k_gates<<<256,  256, 0, stream>>>(x, aw, ab, ew, eb, tw, tb, aet);
  k_scan <<<128,  512, 0, stream>>>(Qb, Kb, KTg, V, aet, iw1, ib1, iw2, ib2,
                                    hkb, hqs, hkT, dvpb, w2Tb, out, bar);
}